// Round 4
// baseline (687.955 us; speedup 1.0000x reference)
//
#include <hip/hip_runtime.h>
#include <hip/hip_fp16.h>
#include <math.h>

#define B_    128
#define NTOK  577
#define KSEL  172
#define M_WG  (B_*NTOK)    // 73856
#define M_SEL (B_*KSEL)    // 22016

typedef float f32x4 __attribute__((ext_vector_type(4)));
typedef short s16x8 __attribute__((ext_vector_type(8)));
typedef short s16x4 __attribute__((ext_vector_type(4)));
typedef _Float16 f16x8 __attribute__((ext_vector_type(8)));

__device__ __forceinline__ unsigned short bf16_rne(float x) {
    unsigned u = __float_as_uint(x);
    u += 0x7FFFu + ((u >> 16) & 1u);
    return (unsigned short)(u >> 16);
}
__device__ __forceinline__ float bf16f(unsigned short h) {
    return __uint_as_float(((unsigned)h) << 16);
}
// async global->LDS 16B: per-lane global src, lane-contiguous LDS dest
__device__ __forceinline__ void gll16(const void* g, void* l) {
    __builtin_amdgcn_global_load_lds(
        (const __attribute__((address_space(1))) unsigned int*)g,
        (__attribute__((address_space(3))) unsigned int*)l, 16, 0, 0);
}

// ---------------- zero init ----------------
__global__ void zero_kernel(float* __restrict__ w, float* __restrict__ stats) {
    int i = blockIdx.x * 256 + threadIdx.x;
    if (i < M_WG) w[i] = 0.f;
    if (i < 1024) stats[i] = 0.f;
}

// ------- weight transpose: wg pair (bf16 h/l) + f16 singles (w0, mw1, fc) -----
__global__ __launch_bounds__(256) void transpose_split_kernel(
    const float* __restrict__ wgw1, const float* __restrict__ mw0,
    const float* __restrict__ mw1, const float* __restrict__ fcw,
    short* __restrict__ w1t_h, short* __restrict__ w1t_l,
    short* __restrict__ w0t, short* __restrict__ mw1t, short* __restrict__ fct)
{
    const int z = blockIdx.z;
    const float* src; short *dh, *dl = nullptr; int N; int bfmode;
    if (z == 0)      { src = wgw1; dh = w1t_h; dl = w1t_l; N = 512;  bfmode = 1; }
    else if (z == 1) { src = mw0;  dh = w0t;   N = 512;  bfmode = 0; }
    else if (z == 2) { src = mw1;  dh = mw1t;  N = 1024; bfmode = 0; }
    else             { src = fcw;  dh = fct;   N = 1024; bfmode = 0; }
    const int n0 = blockIdx.x * 64;
    if (n0 >= N) return;
    const int k0 = blockIdx.y * 64;
    __shared__ float t[64][65];
    const int tid = threadIdx.x;
#pragma unroll
    for (int rr = 0; rr < 16; rr++) {
        int kl = rr * 4 + (tid >> 6);
        int nl = tid & 63;
        t[kl][nl] = src[(size_t)(k0 + kl) * N + n0 + nl];
    }
    __syncthreads();
    const int nl = tid >> 2, kc = tid & 3;
    short hs[16], ls[16];
#pragma unroll
    for (int j = 0; j < 16; j++) {
        float x = t[kc * 16 + j][nl];
        if (bfmode) {
            unsigned short h = bf16_rne(x);
            hs[j] = (short)h;
            ls[j] = (short)bf16_rne(x - bf16f(h));
        } else {
            hs[j] = (short)__half_as_ushort(__float2half(x));
        }
    }
    size_t o = (size_t)(n0 + nl) * 512 + k0 + kc * 16;
    *(s16x8*)(dh + o)     = *(s16x8*)hs;
    *(s16x8*)(dh + o + 8) = *(s16x8*)(hs + 8);
    if (bfmode) {
        *(s16x8*)(dl + o)     = *(s16x8*)ls;
        *(s16x8*)(dl + o + 8) = *(s16x8*)(ls + 8);
    }
}

// -------- wg GEMM (bf16x2, 3 passes): scores = rowsum(relu(F@W1+b1)*v) --------
// LDS k-major [kq][128][8] -> quarter-wave frag reads are 16B-contiguous (no conflicts)
__global__ __launch_bounds__(256) void gemm_wg_kernel(
    const float* __restrict__ F, const short* __restrict__ Wh, const short* __restrict__ Wl,
    const float* __restrict__ b1, const float* __restrict__ v, float* __restrict__ w_out)
{
    __shared__ short Ah[4096], Al[4096], Bh[4096], Bl[4096];
    const int tid = threadIdx.x, lane = tid & 63, w = tid >> 6;
    const int wm = w >> 1, wn = w & 1;
    const int rowbase = blockIdx.y * 128, nbase = blockIdx.x * 128;
    const int r = lane & 15, kq = lane >> 4;
    f32x4 acc[4][4];
#pragma unroll
    for (int i = 0; i < 4; i++)
#pragma unroll
        for (int j = 0; j < 4; j++) acc[i][j] = (f32x4)(0.0f);
    for (int k0 = 0; k0 < 512; k0 += 32) {
        // A: f32 -> bf16 hi/lo split, reg-staged
#pragma unroll
        for (int p = 0; p < 2; p++) {
            int c = tid + p * 256, row = c & 127, kqs = c >> 7;
            const float* s = F + (size_t)(rowbase + row) * 512 + k0 + kqs * 8;
            float4 v0 = *(const float4*)s;
            float4 v1 = *(const float4*)(s + 4);
            float vv[8] = {v0.x, v0.y, v0.z, v0.w, v1.x, v1.y, v1.z, v1.w};
            short hs[8], ls[8];
#pragma unroll
            for (int j = 0; j < 8; j++) {
                unsigned short h = bf16_rne(vv[j]);
                hs[j] = (short)h;
                ls[j] = (short)bf16_rne(vv[j] - bf16f(h));
            }
            *(s16x8*)(Ah + kqs * 1024 + row * 8) = *(s16x8*)hs;
            *(s16x8*)(Al + kqs * 1024 + row * 8) = *(s16x8*)ls;
        }
        // B: pre-split, direct global->LDS
#pragma unroll
        for (int p = 0; p < 2; p++) {
            int c = tid + p * 256, row = c & 127, kqs = c >> 7;
            size_t go = (size_t)(nbase + row) * 512 + k0 + kqs * 8;
            gll16(Wh + go, Bh + c * 8);
            gll16(Wl + go, Bl + c * 8);
        }
        __syncthreads();
        s16x8 ah[4], al[4], bh[4], bl[4];
#pragma unroll
        for (int mf = 0; mf < 4; mf++) {
            int off = kq * 1024 + (wm * 64 + mf * 16 + r) * 8;
            ah[mf] = *(const s16x8*)(Ah + off);
            al[mf] = *(const s16x8*)(Al + off);
        }
#pragma unroll
        for (int nf = 0; nf < 4; nf++) {
            int off = kq * 1024 + (wn * 64 + nf * 16 + r) * 8;
            bh[nf] = *(const s16x8*)(Bh + off);
            bl[nf] = *(const s16x8*)(Bl + off);
        }
#pragma unroll
        for (int mf = 0; mf < 4; mf++)
#pragma unroll
            for (int nf = 0; nf < 4; nf++) {
                acc[mf][nf] = __builtin_amdgcn_mfma_f32_16x16x32_bf16(ah[mf], bh[nf], acc[mf][nf], 0, 0, 0);
                acc[mf][nf] = __builtin_amdgcn_mfma_f32_16x16x32_bf16(ah[mf], bl[nf], acc[mf][nf], 0, 0, 0);
                acc[mf][nf] = __builtin_amdgcn_mfma_f32_16x16x32_bf16(al[mf], bh[nf], acc[mf][nf], 0, 0, 0);
            }
        __syncthreads();
    }
    float b1v[4], vv[4];
#pragma unroll
    for (int nf = 0; nf < 4; nf++) {
        int col = nbase + wn * 64 + nf * 16 + r;
        b1v[nf] = b1[col]; vv[nf] = v[col];
    }
#pragma unroll
    for (int mf = 0; mf < 4; mf++)
#pragma unroll
        for (int i = 0; i < 4; i++) {
            float s = 0.f;
#pragma unroll
            for (int nf = 0; nf < 4; nf++)
                s += fmaxf(acc[mf][nf][i] + b1v[nf], 0.f) * vv[nf];
            s += __shfl_xor(s, 1); s += __shfl_xor(s, 2);
            s += __shfl_xor(s, 4); s += __shfl_xor(s, 8);
            if (r == 0)
                atomicAdd(&w_out[rowbase + wm * 64 + mf * 16 + kq * 4 + i], s);
        }
}

// ---------------- per-batch top-k via bitonic sort (verified) ----------------
__global__ __launch_bounds__(512) void topk_kernel(
    const float* __restrict__ w, int* __restrict__ idx_out)
{
    __shared__ float sval[1024];
    __shared__ int   sidx[1024];
    __shared__ int   s2[256];
    const int b = blockIdx.x;
    const int tid = threadIdx.x;
    for (int i = tid; i < 1024; i += 512) {
        if (i < 576) { sval[i] = w[b * NTOK + 1 + i]; sidx[i] = 1 + i; }
        else         { sval[i] = -1e38f;              sidx[i] = 0x7fffffff; }
    }
    __syncthreads();
    for (int ksz = 2; ksz <= 1024; ksz <<= 1) {
        for (int j = ksz >> 1; j > 0; j >>= 1) {
            int i = ((tid & ~(j - 1)) << 1) | (tid & (j - 1));
            int ixj = i | j;
            float va = sval[i], vb = sval[ixj];
            int ia = sidx[i], ib = sidx[ixj];
            bool a_first = (va > vb) || (va == vb && ia < ib);
            bool dirDesc = ((i & ksz) == 0);
            bool doswap = dirDesc ? (!a_first) : a_first;
            if (doswap) { sval[i] = vb; sval[ixj] = va; sidx[i] = ib; sidx[ixj] = ia; }
            __syncthreads();
        }
    }
    for (int i = tid; i < 256; i += 512) s2[i] = (i < KSEL) ? sidx[i] : 0x7fffffff;
    __syncthreads();
    for (int ksz = 2; ksz <= 256; ksz <<= 1) {
        for (int j = ksz >> 1; j > 0; j >>= 1) {
            if (tid < 128) {
                int i = ((tid & ~(j - 1)) << 1) | (tid & (j - 1));
                int ixj = i | j;
                int a = s2[i], bb = s2[ixj];
                bool asc = ((i & ksz) == 0);
                bool doswap = asc ? (a > bb) : (a < bb);
                if (doswap) { s2[i] = bb; s2[ixj] = a; }
            }
            __syncthreads();
        }
    }
    for (int i = tid; i < KSEL; i += 512) idx_out[b * KSEL + i] = s2[i];
}

// ---------- gather + l2norm -> f16 (matches reference sel.half()) ----------
__global__ __launch_bounds__(128) void gather_norm_kernel(
    const float* __restrict__ F, const int* __restrict__ idx,
    short* __restrict__ Sh)
{
    const int g = blockIdx.x;
    const int b = g / KSEL;
    const int tok = idx[g];
    const float4* src = (const float4*)(F + ((size_t)b * NTOK + tok) * 512);
    const int t = threadIdx.x;
    float4 v = src[t];
    float ss = v.x * v.x + v.y * v.y + v.z * v.z + v.w * v.w;
#pragma unroll
    for (int off = 32; off > 0; off >>= 1) ss += __shfl_down(ss, off);
    __shared__ float red[2];
    if ((t & 63) == 0) red[t >> 6] = ss;
    __syncthreads();
    float inv = 1.0f / (sqrtf(red[0] + red[1]) + 1e-8f);
    float xs[4] = {v.x * inv, v.y * inv, v.z * inv, v.w * inv};
    short hs[4];
#pragma unroll
    for (int j = 0; j < 4; j++) hs[j] = (short)__half_as_ushort(__float2half(xs[j]));
    *(s16x4*)(Sh + (size_t)g * 512 + t * 4) = *(s16x4*)hs;
}

// -------- x1 = f16(sel @ w0 + b0), fused BN-stat partials (f16 MFMA) --------
// tile 128x256, 4 waves (col-split), acc[8][4]
__global__ __launch_bounds__(256) void gemm_x1_kernel(
    const short* __restrict__ Sh, const short* __restrict__ W0t,
    const float* __restrict__ b0, short* __restrict__ X1h, float* __restrict__ stats)
{
    __shared__ short A[4096], Bt[8192];
    const int tid = threadIdx.x, lane = tid & 63, wn = tid >> 6;
    const int rowbase = blockIdx.y * 128, nbase = blockIdx.x * 256;
    const int r = lane & 15, kq = lane >> 4;
    f32x4 acc[8][4];
#pragma unroll
    for (int i = 0; i < 8; i++)
#pragma unroll
        for (int j = 0; j < 4; j++) acc[i][j] = (f32x4)(0.0f);
    for (int k0 = 0; k0 < 512; k0 += 32) {
#pragma unroll
        for (int p = 0; p < 2; p++) {
            int c = tid + p * 256, row = c & 127, kqs = c >> 7;
            gll16(Sh + (size_t)(rowbase + row) * 512 + k0 + kqs * 8, A + c * 8);
        }
#pragma unroll
        for (int p = 0; p < 4; p++) {
            int c = tid + p * 256, col = c & 255, kqs = c >> 8;
            gll16(W0t + (size_t)(nbase + col) * 512 + k0 + kqs * 8, Bt + c * 8);
        }
        __syncthreads();
        f16x8 b[4];
#pragma unroll
        for (int nf = 0; nf < 4; nf++)
            b[nf] = *(const f16x8*)(Bt + kq * 2048 + (wn * 64 + nf * 16 + r) * 8);
#pragma unroll
        for (int mf = 0; mf < 8; mf++) {
            f16x8 a = *(const f16x8*)(A + kq * 1024 + (mf * 16 + r) * 8);
#pragma unroll
            for (int nf = 0; nf < 4; nf++)
                acc[mf][nf] = __builtin_amdgcn_mfma_f32_16x16x32_f16(a, b[nf], acc[mf][nf], 0, 0, 0);
        }
        __syncthreads();
    }
#pragma unroll
    for (int nf = 0; nf < 4; nf++) {
        int col = nbase + wn * 64 + nf * 16 + r;
        float b0v = b0[col];
        float cs = 0.f, cq = 0.f;
#pragma unroll
        for (int mf = 0; mf < 8; mf++)
#pragma unroll
            for (int i = 0; i < 4; i++) {
                int row = rowbase + mf * 16 + kq * 4 + i;
                float val = acc[mf][nf][i] + b0v;
                X1h[(size_t)row * 512 + col] = (short)__half_as_ushort(__float2half(val));
                cs += val; cq += val * val;
            }
        cs += __shfl_xor(cs, 16); cs += __shfl_xor(cs, 32);
        cq += __shfl_xor(cq, 16); cq += __shfl_xor(cq, 32);
        if (kq == 0) {
            atomicAdd(&stats[col], cs);
            atomicAdd(&stats[512 + col], cq);
        }
    }
}

__global__ void bn_finalize_kernel(const float* __restrict__ stats,
                                   const float* __restrict__ g,
                                   const float* __restrict__ b,
                                   float* __restrict__ ss)
{
    int c = threadIdx.x;  // 512
    float mean = stats[c] * (1.0f / M_SEL);
    float var = stats[512 + c] * (1.0f / M_SEL) - mean * mean;
    float sc = g[c] * rsqrtf(var + 1e-5f);
    ss[c] = sc;
    ss[512 + c] = b[c] - mean * sc;
}

// ---- out = f16(sel@fc_w + fc_b) + (bnrelu(x1) @ w1 + b1)  (f16 MFMA) ----
// tile 128x256, acc[8][4]
__global__ __launch_bounds__(256) void gemm_out2_kernel(
    const short* __restrict__ Sh, const short* __restrict__ FCt,
    const float* __restrict__ fcb, const short* __restrict__ X1h,
    const short* __restrict__ W1t, const float* __restrict__ ssbuf,
    const float* __restrict__ b1, float* __restrict__ out)
{
    __shared__ short A[4096], Bt[8192];
    __shared__ float sc[512], sh_[512];
    const int tid = threadIdx.x, lane = tid & 63, wn = tid >> 6;
    const int rowbase = blockIdx.y * 128, nbase = blockIdx.x * 256;
    const int r = lane & 15, kq = lane >> 4;
    for (int i = tid; i < 512; i += 256) { sc[i] = ssbuf[i]; sh_[i] = ssbuf[512 + i]; }
    f32x4 acc[8][4];
#pragma unroll
    for (int i = 0; i < 8; i++)
#pragma unroll
        for (int j = 0; j < 4; j++) acc[i][j] = (f32x4)(0.0f);
    // phase A: fc (f16 operands == reference .half())
    for (int k0 = 0; k0 < 512; k0 += 32) {
#pragma unroll
        for (int p = 0; p < 2; p++) {
            int c = tid + p * 256, row = c & 127, kqs = c >> 7;
            gll16(Sh + (size_t)(rowbase + row) * 512 + k0 + kqs * 8, A + c * 8);
        }
#pragma unroll
        for (int p = 0; p < 4; p++) {
            int c = tid + p * 256, col = c & 255, kqs = c >> 8;
            gll16(FCt + (size_t)(nbase + col) * 512 + k0 + kqs * 8, Bt + c * 8);
        }
        __syncthreads();
        f16x8 b[4];
#pragma unroll
        for (int nf = 0; nf < 4; nf++)
            b[nf] = *(const f16x8*)(Bt + kq * 2048 + (wn * 64 + nf * 16 + r) * 8);
#pragma unroll
        for (int mf = 0; mf < 8; mf++) {
            f16x8 a = *(const f16x8*)(A + kq * 1024 + (mf * 16 + r) * 8);
#pragma unroll
            for (int nf = 0; nf < 4; nf++)
                acc[mf][nf] = __builtin_amdgcn_mfma_f32_16x16x32_f16(a, b[nf], acc[mf][nf], 0, 0, 0);
        }
        __syncthreads();
    }
    // round fc result to f16 and add f16 bias (reference f16 semantics)
#pragma unroll
    for (int nf = 0; nf < 4; nf++) {
        float fb = __half2float(__float2half(fcb[nbase + wn * 64 + nf * 16 + r]));
#pragma unroll
        for (int mf = 0; mf < 8; mf++)
#pragma unroll
            for (int i = 0; i < 4; i++) {
                float t = __half2float(__float2half(acc[mf][nf][i]));
                acc[mf][nf][i] = __half2float(__float2half(t + fb));
            }
    }
    // phase B: bnrelu(x1) @ w1
    for (int k0 = 0; k0 < 512; k0 += 32) {
#pragma unroll
        for (int p = 0; p < 2; p++) {
            int c = tid + p * 256, row = c & 127, kqs = c >> 7;
            s16x8 xi = *(const s16x8*)(X1h + (size_t)(rowbase + row) * 512 + k0 + kqs * 8);
            short hs[8];
#pragma unroll
            for (int j = 0; j < 8; j++) {
                float xf = __half2float(__ushort_as_half((unsigned short)xi[j]));
                int k = k0 + kqs * 8 + j;
                float y = fmaxf(fmaf(xf, sc[k], sh_[k]), 0.f);
                hs[j] = (short)__half_as_ushort(__float2half(y));
            }
            *(s16x8*)(A + kqs * 1024 + row * 8) = *(s16x8*)hs;
        }
#pragma unroll
        for (int p = 0; p < 4; p++) {
            int c = tid + p * 256, col = c & 255, kqs = c >> 8;
            gll16(W1t + (size_t)(nbase + col) * 512 + k0 + kqs * 8, Bt + c * 8);
        }
        __syncthreads();
        f16x8 b[4];
#pragma unroll
        for (int nf = 0; nf < 4; nf++)
            b[nf] = *(const f16x8*)(Bt + kq * 2048 + (wn * 64 + nf * 16 + r) * 8);
#pragma unroll
        for (int mf = 0; mf < 8; mf++) {
            f16x8 a = *(const f16x8*)(A + kq * 1024 + (mf * 16 + r) * 8);
#pragma unroll
            for (int nf = 0; nf < 4; nf++)
                acc[mf][nf] = __builtin_amdgcn_mfma_f32_16x16x32_f16(a, b[nf], acc[mf][nf], 0, 0, 0);
        }
        __syncthreads();
    }
#pragma unroll
    for (int nf = 0; nf < 4; nf++) {
        int col = nbase + wn * 64 + nf * 16 + r;
        float bb = b1[col];
#pragma unroll
        for (int mf = 0; mf < 8; mf++)
#pragma unroll
            for (int i = 0; i < 4; i++) {
                int row = rowbase + mf * 16 + kq * 4 + i;
                out[(size_t)row * 1024 + col] = acc[mf][nf][i] + bb;
            }
    }
}

extern "C" void kernel_launch(void* const* d_in, const int* in_sizes, int n_in,
                              void* d_out, int out_size, void* d_ws, size_t ws_size,
                              hipStream_t stream)
{
    const float* features = (const float*)d_in[0];
    const float* wg_w1 = (const float*)d_in[2];
    const float* wg_b1 = (const float*)d_in[3];
    const float* wg_w2 = (const float*)d_in[4];
    const float* fc_w  = (const float*)d_in[6];
    const float* fc_b  = (const float*)d_in[7];
    const float* mlp_w0 = (const float*)d_in[8];
    const float* mlp_b0 = (const float*)d_in[9];
    const float* bn_g  = (const float*)d_in[10];
    const float* bn_b  = (const float*)d_in[11];
    const float* mlp_w1 = (const float*)d_in[12];
    const float* mlp_b1 = (const float*)d_in[13];
    float* out = (float*)d_out;

    char* ws = (char*)d_ws;
    float* w_scores  = (float*)(ws + 0);          // 73856 f32
    float* stats     = (float*)(ws + 295424);     // 1024 f32
    float* scaleshift= (float*)(ws + 299520);     // 1024 f32
    int*   idx_sel   = (int*)  (ws + 303616);     // 22016 i32
    short* w1t_h     = (short*)(ws + 391680);     // wg_w1^T bf16 hi [512][512]
    short* w1t_l     = (short*)(ws + 915968);     // wg_w1^T bf16 lo
    short* w0t       = (short*)(ws + 1440256);    // mlp_w0^T f16 [512][512]
    short* mw1t      = (short*)(ws + 1964544);    // mlp_w1^T f16 [1024][512]
    short* fct       = (short*)(ws + 3013120);    // fc_w^T  f16 [1024][512]
    short* sel_h     = (short*)(ws + 4061696);    // sel f16 [22016][512]
    short* x1h       = (short*)(ws + 26606080);   // x1  f16 [22016][512]
    // total ws use ≈ 49.2 MB

    zero_kernel<<<289, 256, 0, stream>>>(w_scores, stats);
    transpose_split_kernel<<<dim3(16, 8, 4), 256, 0, stream>>>(
        wg_w1, mlp_w0, mlp_w1, fc_w, w1t_h, w1t_l, w0t, mw1t, fct);
    gemm_wg_kernel<<<dim3(4, 577), 256, 0, stream>>>(
        features, w1t_h, w1t_l, wg_b1, wg_w2, w_scores);
    topk_kernel<<<B_, 512, 0, stream>>>(w_scores, idx_sel);
    gather_norm_kernel<<<M_SEL, 128, 0, stream>>>(features, idx_sel, sel_h);
    gemm_x1_kernel<<<dim3(2, 172), 256, 0, stream>>>(
        sel_h, w0t, mlp_b0, x1h, stats);
    bn_finalize_kernel<<<1, 512, 0, stream>>>(stats, bn_g, bn_b, scaleshift);
    gemm_out2_kernel<<<dim3(4, 172), 256, 0, stream>>>(
        sel_h, fct, fc_b, x1h, mw1t, scaleshift, mlp_b1, out);
}